// Round 4
// baseline (261.167 us; speedup 1.0000x reference)
//
#include <hip/hip_runtime.h>
#include <hip/hip_fp16.h>
#include <stdint.h>

// BATCH=4096, LENGTH=128, FEAT=4, RANK=64, 126 mid sites.
#define NSITES 126
#define XP 520   // xh row pitch in halfs (1040 B -> bank stride 260 mod 32 = 4)

typedef _Float16 half8_t  __attribute__((ext_vector_type(8)));
typedef _Float16 half2_t  __attribute__((ext_vector_type(2)));
typedef float    float4_t __attribute__((ext_vector_type(4)));

// Column permutation: tile u puts m-row m at G-column 64i + rho(u,m); chosen so
// each lane's D-regs after a site ARE the B-frag elements the next site needs.
__device__ __forceinline__ constexpr int rho_map(int u, int m) {
    return 32*(u>>1) + 8*(m>>2) + 4*(u&1) + (m&3);
}

// ---------------------------------------------------------------------------
// Repack mid_cores fp32 [126][64][256] -> fp16 A-fragments (G in the A slot),
// K=256 chunk order: frag f = u*8 + i*2 + h; lane(q,c) element j =
//   G[l = 32h + 8q + j][n = 64i + rho(u,c)]
// ---------------------------------------------------------------------------
__global__ __launch_bounds__(256) void repack_g(const float* __restrict__ mid,
                                                _Float16* __restrict__ gt) {
    __shared__ float lds[64 * 260];
    const int s = blockIdx.x, t = threadIdx.x;
    const float* src = mid + (size_t)s * 16384;
#pragma unroll
    for (int k = 0; k < 16; ++k) {
        const int f4 = t + 256 * k;
        const int l = f4 >> 6, n0 = (f4 & 63) * 4;
        *(float4_t*)&lds[l * 260 + n0] = *(const float4_t*)&src[f4 * 4];
    }
    __syncthreads();
    half8_t* dst = (half8_t*)gt + (size_t)s * 2048;
#pragma unroll
    for (int m = 0; m < 8; ++m) {
        const int F = t + 256 * m;
        const int lane = F & 63, f = F >> 6;
        const int u = f >> 3, i = (f >> 1) & 3, h = f & 1;
        const int q = lane >> 4, c = lane & 15;
        const int n = 64 * i + rho_map(u, c);
        half8_t o;
#pragma unroll
        for (int j = 0; j < 8; ++j)
            o[j] = (_Float16)lds[(32 * h + 8 * q + j) * 260 + n];
        dst[F] = o;
    }
}

__device__ __forceinline__ void gload_lds16(const void* g, void* l) {
    __builtin_amdgcn_global_load_lds(
        (const __attribute__((address_space(1))) void*)g,
        (__attribute__((address_space(3))) void*)l, 16, 0, 0);
}

// ---------------------------------------------------------------------------
// 128 blocks x 64 threads: one wave = one chain of 32 batches. G staged by
// async DMA into two distinct LDS buffers (compiler can't sink DMA — fixes
// round-3's pipeline collapse); explicit vmcnt(32) = 1-site prefetch window.
// x folded into the MFMA B operand (K=256) — no fp32 i-combine VALU.
// No barriers anywhere in the site loop (wave-private block).
// ---------------------------------------------------------------------------
__global__ __launch_bounds__(64, 1) void tt_chain(
    const float* __restrict__ x,      // [4096][128][4]
    const float* __restrict__ first,  // [4][64]
    const float* __restrict__ last,   // [64][4]
    const _Float16* __restrict__ gt,  // frag-ordered fp16, 32 KB/site
    float* __restrict__ out) {        // [4096]

    __shared__ _Float16 gA[16384];
    __shared__ _Float16 gB[16384];
    __shared__ _Float16 xh[32 * XP];

    const int lane = threadIdx.x;
    const int q = lane >> 4, c = lane & 15;
    const int b0 = blockIdx.x * 32;

    // ---- stage x rows b0..b0+31 as fp16 (scalar RTN casts; RTZ pack would
    // compound a -2^-11/site bias over 126 sites)
    {
        const float4_t* src = (const float4_t*)(x + (size_t)b0 * 512);
#pragma unroll
        for (int k = 0; k < 64; ++k) {
            const int f4 = lane + 64 * k;
            const int row = f4 >> 7, col = (f4 & 127) * 4;
            const float4_t v = src[f4];
            half2_t a = { (_Float16)v.x, (_Float16)v.y };
            half2_t b = { (_Float16)v.z, (_Float16)v.w };
            *(half2_t*)&xh[row * XP + col]     = a;
            *(half2_t*)&xh[row * XP + col + 2] = b;
        }
    }

    // ---- v0[b, rho(u,4q+jj)] in fp32 regs (exact x from global)
    float4_t comb[2][4];
#pragma unroll
    for (int g = 0; g < 2; ++g) {
        const float* xr = x + (size_t)(b0 + 16 * g + c) * 512;
        const float xi0 = xr[0], xi1 = xr[1], xi2 = xr[2], xi3 = xr[3];
#pragma unroll
        for (int u = 0; u < 4; ++u) {
            float4_t vv;
#pragma unroll
            for (int jj = 0; jj < 4; ++jj) {
                const int r = rho_map(u, 4 * q + jj);
                vv[jj] = xi0 * first[r] + xi1 * first[64 + r] +
                         xi2 * first[128 + r] + xi3 * first[192 + r];
            }
            comb[g][u] = vv;
        }
    }

    auto STAGE = [&](int s, _Float16* buf) {
        const char* src = (const char*)gt + (size_t)s * 32768 + lane * 16;
        char* dst = (char*)buf + lane * 16;
#pragma unroll
        for (int k = 0; k < 32; ++k)
            gload_lds16(src + k * 1024, dst + k * 1024);
    };

    STAGE(0, gA);
    STAGE(1, gB);
    int e0 = 0, e1 = 0;

    auto SITE = [&](int s, _Float16* buf) {
        // site-s buffer ready; the newest 32 (site s+1's DMA) may stay in flight
        if (s == NSITES - 1) asm volatile("s_waitcnt vmcnt(0)" ::: "memory");
        else                 asm volatile("s_waitcnt vmcnt(32)" ::: "memory");

        // x[b, s+1, i] as replicated half8 per (g,i)
        half8_t xrep[2][4];
#pragma unroll
        for (int g = 0; g < 2; ++g) {
            const half2_t xa = *(const half2_t*)&xh[(16 * g + c) * XP + (s + 1) * 4];
            const half2_t xb = *(const half2_t*)&xh[(16 * g + c) * XP + (s + 1) * 4 + 2];
            const _Float16 xi[4] = { xa[0], xa[1], xb[0], xb[1] };
#pragma unroll
            for (int i = 0; i < 4; ++i) {
                half8_t r;
#pragma unroll
                for (int j = 0; j < 8; ++j) r[j] = xi[i];
                xrep[g][i] = r;
            }
        }

        // B-frags: bf[g][i*2+h][j] = fp16(v[l=32h+8q+j]) * fp16(x_i)
        half8_t bf[2][8];
#pragma unroll
        for (int g = 0; g < 2; ++g)
#pragma unroll
            for (int h = 0; h < 2; ++h) {
                half8_t vh;
#pragma unroll
                for (int jj = 0; jj < 4; ++jj) {
                    vh[jj]     = (_Float16)comb[g][2 * h][jj];
                    vh[4 + jj] = (_Float16)comb[g][2 * h + 1][jj];
                }
#pragma unroll
                for (int i = 0; i < 4; ++i)
                    bf[g][i * 2 + h] = vh * xrep[g][i];
            }

        // K=256 MFMA chains; D = v_{s+1} directly (x already folded in)
        const float4_t z0 = {0.f, 0.f, 0.f, 0.f};
#pragma unroll
        for (int u = 0; u < 4; ++u) {
            half8_t af[8];
#pragma unroll
            for (int kk = 0; kk < 8; ++kk)
                af[kk] = *(const half8_t*)(buf + (u * 8 + kk) * 512 + lane * 8);
            float4_t zg0 = z0, zg1 = z0;
#pragma unroll
            for (int kk = 0; kk < 8; ++kk) {
                zg0 = __builtin_amdgcn_mfma_f32_16x16x32_f16(af[kk], bf[0][kk], zg0, 0, 0, 0);
                zg1 = __builtin_amdgcn_mfma_f32_16x16x32_f16(af[kk], bf[1][kk], zg1, 0, 0, 0);
            }
            comb[0][u] = zg0;
            comb[1][u] = zg1;
        }

        // wave-local per-batch power-of-2 renorm every 8 sites
        if (((s + 1) & 7) == 0) {
            float m0 = 0.f, m1 = 0.f;
#pragma unroll
            for (int u = 0; u < 4; ++u)
#pragma unroll
                for (int jj = 0; jj < 4; ++jj) {
                    m0 = fmaxf(m0, fabsf(comb[0][u][jj]));
                    m1 = fmaxf(m1, fabsf(comb[1][u][jj]));
                }
            m0 = fmaxf(m0, __shfl_xor(m0, 16)); m0 = fmaxf(m0, __shfl_xor(m0, 32));
            m1 = fmaxf(m1, __shfl_xor(m1, 16)); m1 = fmaxf(m1, __shfl_xor(m1, 32));
            int ee0 = 0, ee1 = 0;
            if (m0 > 0.f) frexpf(m0, &ee0);
            if (m1 > 0.f) frexpf(m1, &ee1);
            const float sc0 = ldexpf(1.f, -ee0), sc1 = ldexpf(1.f, -ee1);
#pragma unroll
            for (int u = 0; u < 4; ++u) { comb[0][u] *= sc0; comb[1][u] *= sc1; }
            e0 += ee0; e1 += ee1;
        }

        // prefetch site s+2 into this (fully consumed) buffer
        if (s + 2 < NSITES) {
            asm volatile("s_waitcnt lgkmcnt(0)" ::: "memory");  // ds_reads drained
            STAGE(s + 2, buf);
        }
    };

    for (int s = 0; s < NSITES; s += 2) {
        SITE(s, gA);       // static gA/gB lets AA keep DMA & ds_read apart
        SITE(s + 1, gB);
    }

    // ---- epilogue: out[b] = 2^e * sum_r v126[b][r] * (sum_i last[r][i] x[b][127][i])
    {
        const float4_t xl0 = *(const float4_t*)(x + (size_t)(b0 + c) * 512 + 508);
        const float4_t xl1 = *(const float4_t*)(x + (size_t)(b0 + 16 + c) * 512 + 508);
        float dot0 = 0.f, dot1 = 0.f;
#pragma unroll
        for (int u = 0; u < 4; ++u)
#pragma unroll
            for (int jj = 0; jj < 4; ++jj) {
                const int r = rho_map(u, 4 * q + jj);
                const float4_t lr = *(const float4_t*)&last[r * 4];
                const float lv0 = lr[0]*xl0[0] + lr[1]*xl0[1] + lr[2]*xl0[2] + lr[3]*xl0[3];
                const float lv1 = lr[0]*xl1[0] + lr[1]*xl1[1] + lr[2]*xl1[2] + lr[3]*xl1[3];
                dot0 += comb[0][u][jj] * lv0;
                dot1 += comb[1][u][jj] * lv1;
            }
        dot0 += __shfl_xor(dot0, 16); dot0 += __shfl_xor(dot0, 32);
        dot1 += __shfl_xor(dot1, 16); dot1 += __shfl_xor(dot1, 32);
        if (lane < 16)      out[b0 + lane] = ldexpf(dot0, e0);
        else if (lane < 32) out[b0 + lane] = ldexpf(dot1, e1);
    }
}

extern "C" void kernel_launch(void* const* d_in, const int* in_sizes, int n_in,
                              void* d_out, int out_size, void* d_ws, size_t ws_size,
                              hipStream_t stream) {
    (void)in_sizes; (void)n_in; (void)out_size; (void)ws_size;
    const float* x     = (const float*)d_in[0];
    const float* first = (const float*)d_in[1];
    const float* mid   = (const float*)d_in[2];
    const float* last  = (const float*)d_in[3];
    float* out = (float*)d_out;
    _Float16* gt = (_Float16*)d_ws;   // 126*2048*16 B = 4,128,768 B

    repack_g<<<126, 256, 0, stream>>>(mid, gt);
    tt_chain<<<128, 64, 0, stream>>>(x, first, last, gt, out);
}

// Round 5
// 121.536 us; speedup vs baseline: 2.1489x; 2.1489x over previous
//
#include <hip/hip_runtime.h>
#include <hip/hip_fp16.h>
#include <stdint.h>

// BATCH=4096, LENGTH=128, FEAT=4, RANK=64, 126 mid sites.
#define NSITES 126
#define XPITCH 516                 // xbuf row pitch (floats)
#define VPITCH 68                  // vbuf row pitch (floats)

typedef _Float16 half8_t  __attribute__((ext_vector_type(8)));
typedef float    float4_t __attribute__((ext_vector_type(4)));

// light barrier: LDS-only drain; asm G-loads (vmcnt) stay in flight across it
#define LBAR() asm volatile("s_waitcnt lgkmcnt(0)\n\ts_barrier" ::: "memory")
// explicit wait: oldest loads complete when <=N remain outstanding
#define WAITV(N) asm volatile("s_waitcnt vmcnt(" #N ")" ::: "memory")
// zero-instruction tie: forces the 8 frag values through a volatile asm node,
// so MFMAs (pure ops) cannot be scheduled above the preceding WAITV
#define TIE8(F) asm volatile("" : "+v"(F[0]), "+v"(F[1]), "+v"(F[2]), "+v"(F[3]), \
                                  "+v"(F[4]), "+v"(F[5]), "+v"(F[6]), "+v"(F[7]))

// volatile asm load: compiler cannot sink/remat this (fixes R2's collapsed
// register pipeline, VGPR_Count=80 -> frags provably live in VGPRs now)
__device__ __forceinline__ void aload(half8_t& d, const void* p) {
    asm volatile("global_load_dwordx4 %0, %1, off" : "=v"(d) : "v"(p));
}

// ---------------------------------------------------------------------------
// Repack mid_cores fp32 [126][64][256] -> fp16 B-fragments in exact lane
// order: frag F = ((i*2+h)*4 + w)*64 + lane, 16B each; element j of frag =
// G[l = 32h + 8q + j][n = i*64 + w*16 + c]  (lane = q*16+c).
// ---------------------------------------------------------------------------
__global__ __launch_bounds__(256) void repack_g(const float* __restrict__ mid,
                                                _Float16* __restrict__ gt) {
    __shared__ float lds[64 * 260];
    const int s = blockIdx.x;
    const int t = threadIdx.x;
    const float* src = mid + (size_t)s * 16384;
#pragma unroll
    for (int k = 0; k < 16; ++k) {
        const int f4 = t + 256 * k;              // float4 index 0..4095
        const int l = f4 >> 6, n0 = (f4 & 63) * 4;
        *(float4_t*)&lds[l * 260 + n0] = *(const float4_t*)&src[f4 * 4];
    }
    __syncthreads();
    half8_t* dst = (half8_t*)gt + (size_t)s * 2048;
#pragma unroll
    for (int m = 0; m < 8; ++m) {
        const int F = t + 256 * m;               // 0..2047
        const int lane = F & 63, w = (F >> 6) & 3, h = (F >> 8) & 1, i = F >> 9;
        const int q = lane >> 4, c = lane & 15;
        const int n = i * 64 + w * 16 + c;
        half8_t o;
#pragma unroll
        for (int j = 0; j < 8; ++j)
            o[j] = (_Float16)lds[(32 * h + 8 * q + j) * 260 + n];
        dst[F] = o;
    }
}

// ---------------------------------------------------------------------------
// Main chain: 256 blocks x 256 threads (1 block/CU, 16 batches/CU, 4 waves
// on 4 SIMDs). Wave w owns r-cols [16w,16w+16). G fragments held in VGPRs,
// loaded by volatile-asm global loads with a 2-site prefetch pipeline and
// manual vmcnt(16) waits. One lgkm-only barrier per site for the v' exchange.
// ---------------------------------------------------------------------------
__global__ __launch_bounds__(256) void tt_chain(
    const float* __restrict__ x,      // [4096][128][4]
    const float* __restrict__ first,  // [4][64]
    const float* __restrict__ last,   // [64][4]
    const _Float16* __restrict__ gt,  // frag-ordered fp16, 32 KB/site
    float* __restrict__ out) {        // [4096]

    __shared__ float vbuf[2][16 * VPITCH];
    __shared__ float xbuf[16 * XPITCH];
    __shared__ int   eacc[16];

    const int tid  = threadIdx.x;
    const int w    = tid >> 6;
    const int lane = tid & 63;
    const int q    = lane >> 4;
    const int c    = lane & 15;
    const int b0   = blockIdx.x * 16;

    // stage x: 16 rows x 512 floats, coalesced
    {
        const int bb = tid >> 4, seg = tid & 15;
        const float4_t* src = (const float4_t*)(x + (size_t)(b0 + bb) * 512 + seg * 32);
        float4_t* dst = (float4_t*)(xbuf + bb * XPITCH + seg * 32);
#pragma unroll
        for (int k = 0; k < 8; ++k) dst[k] = src[k];
    }
    if (tid < 16) eacc[tid] = 0;
    __syncthreads();

    // v0[b,r] = sum_i x[b,0,i] * first[i,r]
    {
        const int bb = tid >> 4, rq = tid & 15;
        const float xs0 = xbuf[bb * XPITCH + 0], xs1 = xbuf[bb * XPITCH + 1];
        const float xs2 = xbuf[bb * XPITCH + 2], xs3 = xbuf[bb * XPITCH + 3];
#pragma unroll
        for (int k = 0; k < 4; ++k) {
            const int r = rq * 4 + k;
            vbuf[0][bb * VPITCH + r] =
                xs0 * first[r] + xs1 * first[64 + r] + xs2 * first[128 + r] + xs3 * first[192 + r];
        }
    }

    // G register pipeline: per wave 8 frags/site at byte offset
    // s*32768 + ih*4096 + w*1024 + lane*16
    half8_t F0[8], F1[8], F2[8];
    const char* gbase = (const char*)gt + w * 1024 + lane * 16;
    auto LOAD = [&](int s, half8_t* F) {
        const char* p = gbase + (size_t)s * 32768;
#pragma unroll
        for (int ih = 0; ih < 8; ++ih) aload(F[ih], p + ih * 4096);
    };
    LOAD(0, F0);    // outstanding: 8
    LOAD(1, F1);    // outstanding: 16
    LBAR();         // vbuf[0] visible (lgkm only; G loads stay in flight)

    auto STEP = [&](int s, half8_t* F) {
        // invariant: 24 outstanding here; oldest 8 = this site's frags
        WAITV(16);
        TIE8(F);

        const int p = s & 1;
        const float* vr = &vbuf[p][c * VPITCH];
        float4_t a0lo = *(const float4_t*)(vr + q * 8);
        float4_t a0hi = *(const float4_t*)(vr + q * 8 + 4);
        float4_t a1lo = *(const float4_t*)(vr + 32 + q * 8);
        float4_t a1hi = *(const float4_t*)(vr + 32 + q * 8 + 4);

        // wave-local per-batch power-of-2 renorm every 8 sites
        if ((s & 7) == 0 && s != 0) {
            float m = 0.f;
#pragma unroll
            for (int k = 0; k < 4; ++k) {
                m = fmaxf(m, fabsf(a0lo[k])); m = fmaxf(m, fabsf(a0hi[k]));
                m = fmaxf(m, fabsf(a1lo[k])); m = fmaxf(m, fabsf(a1hi[k]));
            }
            m = fmaxf(m, __shfl_xor(m, 16));
            m = fmaxf(m, __shfl_xor(m, 32));
            int e = 0;
            if (m > 0.f) frexpf(m, &e);
            const float sc = ldexpf(1.0f, -e);
#pragma unroll
            for (int k = 0; k < 4; ++k) {
                a0lo[k] *= sc; a0hi[k] *= sc; a1lo[k] *= sc; a1hi[k] *= sc;
            }
            if (tid < 16) eacc[tid] += e;   // wave 0, q=0: lane==c==batch
        }

        half8_t af0, af1;
#pragma unroll
        for (int k = 0; k < 4; ++k) {
            af0[k] = (_Float16)a0lo[k]; af0[4 + k] = (_Float16)a0hi[k];
            af1[k] = (_Float16)a1lo[k]; af1[4 + k] = (_Float16)a1hi[k];
        }

        float4_t xs[4];
#pragma unroll
        for (int jj = 0; jj < 4; ++jj)
            xs[jj] = *(const float4_t*)(xbuf + (q * 4 + jj) * XPITCH + (s + 1) * 4);

        float4_t acc[4];
#pragma unroll
        for (int i = 0; i < 4; ++i) {
            float4_t z = {0.f, 0.f, 0.f, 0.f};
            z = __builtin_amdgcn_mfma_f32_16x16x32_f16(af0, F[i * 2 + 0], z, 0, 0, 0);
            z = __builtin_amdgcn_mfma_f32_16x16x32_f16(af1, F[i * 2 + 1], z, 0, 0, 0);
            acc[i] = z;
        }

#pragma unroll
        for (int jj = 0; jj < 4; ++jj) {
            const float vn = xs[jj].x * acc[0][jj] + xs[jj].y * acc[1][jj] +
                             xs[jj].z * acc[2][jj] + xs[jj].w * acc[3][jj];
            vbuf[p ^ 1][(q * 4 + jj) * VPITCH + w * 16 + c] = vn;
        }
        LBAR();
    };

    for (int s = 0; s < NSITES; s += 3) {
        const int s2 = (s + 2 < NSITES) ? s + 2 : NSITES - 1;
        const int s3 = (s + 3 < NSITES) ? s + 3 : NSITES - 1;
        const int s4 = (s + 4 < NSITES) ? s + 4 : NSITES - 1;
        LOAD(s2, F2);          // every STEP is preceded by exactly one 8-load
        STEP(s, F0);           // LOAD -> WAITV(16) invariant holds throughout
        LOAD(s3, F0);
        STEP(s + 1, F1);
        LOAD(s4, F1);
        STEP(s + 2, F2);
    }
    WAITV(0);   // drain tail (clamped re-loads of site 125)

    // final v in vbuf[0] (126 even); out[b] = 2^eacc * sum_r v*last_vec
    {
        const int bb = tid >> 4, rq = tid & 15;
        const float x0 = xbuf[bb * XPITCH + 508], x1 = xbuf[bb * XPITCH + 509];
        const float x2 = xbuf[bb * XPITCH + 510], x3 = xbuf[bb * XPITCH + 511];
        float dot = 0.f;
#pragma unroll
        for (int k = 0; k < 4; ++k) {
            const int r = rq * 4 + k;
            const float lv = last[r * 4 + 0] * x0 + last[r * 4 + 1] * x1 +
                             last[r * 4 + 2] * x2 + last[r * 4 + 3] * x3;
            dot += lv * vbuf[0][bb * VPITCH + r];
        }
#pragma unroll
        for (int o = 8; o > 0; o >>= 1) dot += __shfl_xor(dot, o, 16);
        if (rq == 0) out[b0 + bb] = ldexpf(dot, eacc[bb]);
    }
}

extern "C" void kernel_launch(void* const* d_in, const int* in_sizes, int n_in,
                              void* d_out, int out_size, void* d_ws, size_t ws_size,
                              hipStream_t stream) {
    (void)in_sizes; (void)n_in; (void)out_size; (void)ws_size;
    const float* x     = (const float*)d_in[0];
    const float* first = (const float*)d_in[1];
    const float* mid   = (const float*)d_in[2];
    const float* last  = (const float*)d_in[3];
    float* out = (float*)d_out;
    _Float16* gt = (_Float16*)d_ws;   // 126*2048*16 B = 4,128,768 B

    repack_g<<<126, 256, 0, stream>>>(mid, gt);
    tt_chain<<<256, 256, 0, stream>>>(x, first, last, gt, out);
}